// Round 13
// baseline (330.378 us; speedup 1.0000x reference)
//
#include <hip/hip_runtime.h>
#include <hip/hip_bf16.h>
#include <math.h>

#define B_   4
#define CIN  64
#define P_   1728
#define N_   1729
#define C_   256
#define NH_  8
#define HD_  32
#define M_   (B_*N_)   // 6916 rows
#define NPAD 1792      // 28 * 64

typedef __bf16 bf16x8 __attribute__((ext_vector_type(8)));
typedef __bf16 bf16x4 __attribute__((ext_vector_type(4)));
typedef float  f32x4  __attribute__((ext_vector_type(4)));

#if __has_builtin(__builtin_amdgcn_mfma_f32_16x16x16_bf16)
#define MFMA16(A,B,C) __builtin_amdgcn_mfma_f32_16x16x16_bf16(A,B,C,0,0,0)
#else
typedef short s16x4 __attribute__((ext_vector_type(4)));
#define MFMA16(A,B,C) __builtin_amdgcn_mfma_f32_16x16x16bf16_1k( \
    __builtin_bit_cast(s16x4,(A)), __builtin_bit_cast(s16x4,(B)), (C), 0,0,0)
#endif

// ---------------------------------------------------------------------------
// Patch embed. One thread per (b, n, c). Writes t fp32.
// ---------------------------------------------------------------------------
__global__ __launch_bounds__(256) void embed2(
    const float* __restrict__ x, const float* __restrict__ Wpe,
    const float* __restrict__ bpe, const float* __restrict__ cls,
    float* __restrict__ t)
{
    int idx = blockIdx.x*256 + threadIdx.x;        // [0, B*N*C)
    int c   = idx & 255;
    int n   = (idx >> 8) % N_;
    int b   = idx / (N_*256);
    if (n == 0) { t[idx] = cls[c]; return; }
    int p = n - 1;
    float acc = bpe[c];
    for (int ci = 0; ci < CIN; ++ci)
        acc += x[(size_t)(b*CIN + ci)*P_ + p] * Wpe[ci*C_ + c];
    t[idx] = acc;
}

// ---------------------------------------------------------------------------
// ln4: LayerNorm, 4 rows/block (one wave each), float4 in, bf16x4 out.
// ---------------------------------------------------------------------------
__global__ __launch_bounds__(256) void ln4(
    const float* __restrict__ in, __bf16* __restrict__ out,
    const float* __restrict__ g, const float* __restrict__ bb)
{
    int wv = threadIdx.x >> 6, lane = threadIdx.x & 63;
    size_t row = (size_t)blockIdx.x*4 + wv;
    float4 v = *(const float4*)&in[row*C_ + lane*4];
    float s1 = (v.x+v.y)+(v.z+v.w);
    float s2 = (v.x*v.x+v.y*v.y)+(v.z*v.z+v.w*v.w);
    #pragma unroll
    for (int off = 32; off >= 1; off >>= 1) {
        s1 += __shfl_xor(s1, off);
        s2 += __shfl_xor(s2, off);
    }
    float mean = s1*(1.0f/C_);
    float var  = fmaxf(s2*(1.0f/C_) - mean*mean, 0.0f);
    float rstd = rsqrtf(var + 1e-5f);
    float4 gg = *(const float4*)&g[lane*4];
    float4 bv = *(const float4*)&bb[lane*4];
    bf16x4 r;
    r[0] = (__bf16)((v.x-mean)*rstd*gg.x + bv.x);
    r[1] = (__bf16)((v.y-mean)*rstd*gg.y + bv.y);
    r[2] = (__bf16)((v.z-mean)*rstd*gg.z + bv.z);
    r[3] = (__bf16)((v.w-mean)*rstd*gg.w + bv.w);
    *(bf16x4*)&out[row*C_ + lane*4] = r;
}

// ln4f: final norm — fp32 out + cls extraction.
__global__ __launch_bounds__(256) void ln4f(
    const float* __restrict__ in, float* __restrict__ out,
    const float* __restrict__ g, const float* __restrict__ bb,
    float* __restrict__ cls_out)
{
    int wv = threadIdx.x >> 6, lane = threadIdx.x & 63;
    size_t row = (size_t)blockIdx.x*4 + wv;
    float4 v = *(const float4*)&in[row*C_ + lane*4];
    float s1 = (v.x+v.y)+(v.z+v.w);
    float s2 = (v.x*v.x+v.y*v.y)+(v.z*v.z+v.w*v.w);
    #pragma unroll
    for (int off = 32; off >= 1; off >>= 1) {
        s1 += __shfl_xor(s1, off);
        s2 += __shfl_xor(s2, off);
    }
    float mean = s1*(1.0f/C_);
    float var  = fmaxf(s2*(1.0f/C_) - mean*mean, 0.0f);
    float rstd = rsqrtf(var + 1e-5f);
    float4 gg = *(const float4*)&g[lane*4];
    float4 bv = *(const float4*)&bb[lane*4];
    float4 r;
    r.x = (v.x-mean)*rstd*gg.x + bv.x;
    r.y = (v.y-mean)*rstd*gg.y + bv.y;
    r.z = (v.z-mean)*rstd*gg.z + bv.z;
    r.w = (v.w-mean)*rstd*gg.w + bv.w;
    *(float4*)&out[row*C_ + lane*4] = r;
    if ((row % N_) == 0)
        *(float4*)&cls_out[(row / N_)*C_ + lane*4] = r;
}

// ---------------------------------------------------------------------------
// wprep2: all 8 weight matrices -> bf16 W^T[n][k] in one launch.
// ---------------------------------------------------------------------------
__global__ __launch_bounds__(256) void wprep2(
    const float* __restrict__ Wqkv, const float* __restrict__ Wproj,
    const float* __restrict__ W1,   const float* __restrict__ W2,
    __bf16* __restrict__ wT)
{
    int z = blockIdx.z, which = z >> 1, layer = z & 1;
    const float* src; __bf16* dst; int NC;
    if (which == 0) {
        src = Wqkv + (size_t)layer*C_*768;
        dst = wT   + (size_t)layer*768*256;
        NC  = 768;
    } else {
        NC = 256;
        const float* b3 = (which == 1) ? Wproj : (which == 2) ? W1 : W2;
        src = b3 + (size_t)layer*65536;
        dst = wT + 2*768*256 + (size_t)((which-1)*2 + layer)*65536;
    }
    int n0 = blockIdx.x*32; if (n0 >= NC) return;
    int k0 = blockIdx.y*32;
    __shared__ float tile[32][33];
    int c = threadIdx.x & 31, r = threadIdx.x >> 5;
    for (int rr = r; rr < 32; rr += 8)
        tile[rr][c] = src[(size_t)(k0+rr)*NC + n0 + c];
    __syncthreads();
    for (int rr = r; rr < 32; rr += 8)
        dst[(size_t)(n0+rr)*256 + k0 + c] = (__bf16)tile[c][rr];
}

// ---------------------------------------------------------------------------
// gemm3: out[M,NC] (+)= A[M,256](bf16) @ WtT (+bias fp32)(gelu). 64x64 tile,
// BK=32, XOR-swizzled dense LDS.
// ---------------------------------------------------------------------------
template<int NC, bool ADD, bool GELU, bool BIAS, bool OUTBF>
__global__ __launch_bounds__(256) void gemm3(
    const __bf16* __restrict__ A, const __bf16* __restrict__ Wt,
    const float* __restrict__ bias, float* __restrict__ outF,
    __bf16* __restrict__ outB)
{
    __shared__ __align__(16) __bf16 As[64*32];
    __shared__ __align__(16) __bf16 Bs[64*32];
    int r0 = blockIdx.x*64, c0 = blockIdx.y*64;
    int tid = threadIdx.x;
    int wv = tid >> 6, lane = tid & 63, quad = lane >> 4, mn = lane & 15;
    int sr = tid >> 2, sc = tid & 3;
    int ga = r0 + sr; if (ga >= M_) ga = M_ - 1;

    f32x4 acc[4];
    #pragma unroll
    for (int ct = 0; ct < 4; ++ct)
        #pragma unroll
        for (int rr = 0; rr < 4; ++rr) acc[ct][rr] = 0.f;

    for (int kc = 0; kc < 8; ++kc) {
        __syncthreads();
        *(bf16x8*)&As[sr*32 + ((sc ^ (sr & 3))*8)] =
            *(const bf16x8*)&A[(size_t)ga*256 + kc*32 + sc*8];
        *(bf16x8*)&Bs[sr*32 + ((sc ^ (sr & 3))*8)] =
            *(const bf16x8*)&Wt[(size_t)(c0+sr)*256 + kc*32 + sc*8];
        __syncthreads();

        bf16x8 a = *(const bf16x8*)&As[(wv*16 + mn)*32 + ((quad ^ (mn & 3))*8)];
        #pragma unroll
        for (int ct = 0; ct < 4; ++ct) {
            bf16x8 b = *(const bf16x8*)&Bs[(ct*16 + mn)*32 + ((quad ^ (mn & 3))*8)];
            acc[ct] = __builtin_amdgcn_mfma_f32_16x16x32_bf16(a, b, acc[ct], 0, 0, 0);
        }
    }

    #pragma unroll
    for (int ct = 0; ct < 4; ++ct) {
        int col = c0 + ct*16 + mn;
        #pragma unroll
        for (int rr = 0; rr < 4; ++rr) {
            int row = r0 + wv*16 + quad*4 + rr;
            if (row >= M_) continue;
            float val = acc[ct][rr];
            if (BIAS) val += bias[col];
            if (GELU) val = 0.5f*val*(1.f + erff(val*0.70710678118654752f));
            size_t oi = (size_t)row*NC + col;
            if (OUTBF) outB[oi] = (__bf16)val;
            else if (ADD) outF[oi] += val;
            else outF[oi] = val;
        }
    }
}

// ---------------------------------------------------------------------------
// gemm_qkv3: A bf16, NC=768; epilogue packs qB (scaled), kB, vB (transposed).
// ---------------------------------------------------------------------------
__global__ __launch_bounds__(256) void gemm_qkv3(
    const __bf16* __restrict__ A, const __bf16* __restrict__ Wt,
    __bf16* __restrict__ qB, __bf16* __restrict__ kB, __bf16* __restrict__ vB)
{
    __shared__ __align__(16) __bf16 As[64*32];
    __shared__ __align__(16) __bf16 Bs[64*32];
    int r0 = blockIdx.x*64, c0 = blockIdx.y*64;
    int tid = threadIdx.x;
    int wv = tid >> 6, lane = tid & 63, quad = lane >> 4, mn = lane & 15;
    int sr = tid >> 2, sc = tid & 3;
    int ga = r0 + sr; if (ga >= M_) ga = M_ - 1;

    f32x4 acc[4];
    #pragma unroll
    for (int ct = 0; ct < 4; ++ct)
        #pragma unroll
        for (int rr = 0; rr < 4; ++rr) acc[ct][rr] = 0.f;

    for (int kc = 0; kc < 8; ++kc) {
        __syncthreads();
        *(bf16x8*)&As[sr*32 + ((sc ^ (sr & 3))*8)] =
            *(const bf16x8*)&A[(size_t)ga*256 + kc*32 + sc*8];
        *(bf16x8*)&Bs[sr*32 + ((sc ^ (sr & 3))*8)] =
            *(const bf16x8*)&Wt[(size_t)(c0+sr)*256 + kc*32 + sc*8];
        __syncthreads();

        bf16x8 a = *(const bf16x8*)&As[(wv*16 + mn)*32 + ((quad ^ (mn & 3))*8)];
        #pragma unroll
        for (int ct = 0; ct < 4; ++ct) {
            bf16x8 b = *(const bf16x8*)&Bs[(ct*16 + mn)*32 + ((quad ^ (mn & 3))*8)];
            acc[ct] = __builtin_amdgcn_mfma_f32_16x16x32_bf16(a, b, acc[ct], 0, 0, 0);
        }
    }

    const float scale = 0.17677669529663687f;   // 1/sqrt(32)
    #pragma unroll
    for (int ct = 0; ct < 4; ++ct) {
        int col = c0 + ct*16 + mn;
        #pragma unroll
        for (int rr = 0; rr < 4; ++rr) {
            int row = r0 + wv*16 + quad*4 + rr;
            if (row >= M_) continue;
            int b = row / N_, n = row - b*N_;
            float val = acc[ct][rr];
            if (col < 256) {
                int h = col >> 5, dd = col & 31;
                qB[((size_t)(b*NH_+h)*NPAD + n)*32 + dd] = (__bf16)(val*scale);
            } else if (col < 512) {
                int h = (col-256) >> 5, dd = col & 31;
                kB[((size_t)(b*NH_+h)*NPAD + n)*32 + dd] = (__bf16)val;
            } else {
                int h = (col-512) >> 5, dd = col & 31;
                vB[((size_t)(b*NH_+h)*32 + dd)*NPAD + n] = (__bf16)val;
            }
        }
    }
}

// ---------------------------------------------------------------------------
// attn9: MFMA flash attention, P stays in registers.
// S^T = K-frag x Q-frag (16x16x32): C/D lane (quad,mn) = S^T[key=quad*4+rr][q=mn].
// exp in-register -> P is ALREADY a valid 16x16x16 B-frag ([n=q=mn][k=quad*4+j]).
// PV: O^T += V^T-frag x P-frag (16x16x16, d-halves as two accs). l = VALU sums.
// Epilogue: O^T -> lk (reused) -> coalesced bf16x8 stores.
// ---------------------------------------------------------------------------
__global__ __launch_bounds__(256) void attn9(
    const __bf16* __restrict__ qB, const __bf16* __restrict__ kB,
    const __bf16* __restrict__ vB, __bf16* __restrict__ o)
{
    int bh = blockIdx.x, b = bh >> 3, h = bh & 7;
    int q0 = blockIdx.y * 64;
    int tid = threadIdx.x;
    int wv = tid >> 6, lane = tid & 63, quad = lane >> 4, mn = lane & 15;

    __shared__ __align__(16) __bf16 lk[64*32];     // [key][d] swizzled; reused for epilogue
    __shared__ __align__(16) __bf16 lvt[32*64];    // [d][key] swizzled

    // Q as B-operand frag: [n=q=mn][k=d=quad*8+j]
    bf16x8 qfrag = *(const bf16x8*)(
        qB + ((size_t)bh*NPAD + q0 + wv*16 + mn)*32 + quad*8);

    f32x4 oaccA, oaccB;     // O^T: lane holds O[q=mn][d=quad*4+rr] (A: d<16, B: d>=16)
    #pragma unroll
    for (int rr = 0; rr < 4; ++rr) { oaccA[rr]=0.f; oaccB[rr]=0.f; }
    float lsum = 0.f;

    const __bf16* kbase = kB + (size_t)bh*NPAD*32;
    const __bf16* vbase = vB + (size_t)bh*32*NPAD;
    int sr = tid >> 2, sc = tid & 3;     // K staging: 64 rows x 4 chunks
    int vr = tid >> 3, vc = tid & 7;     // V^T staging: 32 rows x 8 chunks

    for (int t = 0; t < 28; ++t) {
        int k0 = t*64;
        __syncthreads();
        *(bf16x8*)&lk[sr*32 + ((sc ^ (sr & 3))*8)] =
            *(const bf16x8*)(kbase + (size_t)(k0 + sr)*32 + sc*8);
        *(bf16x8*)&lvt[vr*64 + ((vc ^ (vr & 7))*8)] =
            *(const bf16x8*)(vbase + (size_t)vr*NPAD + k0 + vc*8);
        __syncthreads();

        #pragma unroll
        for (int ct = 0; ct < 4; ++ct) {
            // S^T tile: A = K rows (16 keys), B = Q  -> lane: S^T[quad*4+rr][mn]
            bf16x8 kf = *(const bf16x8*)&lk[(ct*16 + mn)*32 + ((quad ^ (mn & 3))*8)];
            f32x4 z;
            #pragma unroll
            for (int rr = 0; rr < 4; ++rr) z[rr] = 0.f;
            f32x4 st = __builtin_amdgcn_mfma_f32_16x16x32_bf16(kf, qfrag, z, 0, 0, 0);

            // P = exp(S^T) masked -> B-frag for 16x16x16 PV; l partial sums
            bf16x4 pf;
            #pragma unroll
            for (int rr = 0; rr < 4; ++rr) {
                bool valid = (k0 + ct*16 + quad*4 + rr) < N_;
                float p = valid ? __expf(st[rr]) : 0.f;
                pf[rr] = (__bf16)p;
                lsum += p;
            }

            // V^T A-frags (b64 reads from swizzled lvt): [m=d][k=quad*4+j]
            int chunk = ct*2 + (quad >> 1);
            int sub   = (quad & 1) * 4;
            bf16x4 vloA = *(const bf16x4*)&lvt[ mn      *64 + ((chunk ^ (mn & 7))*8) + sub];
            bf16x4 vloB = *(const bf16x4*)&lvt[(mn+16)*64 + ((chunk ^ (mn & 7))*8) + sub];
            oaccA = MFMA16(vloA, pf, oaccA);
            oaccB = MFMA16(vloB, pf, oaccB);
        }
    }

    // l: reduce across quads (each lane's scores were all for q=mn)
    lsum += __shfl_xor(lsum, 16);
    lsum += __shfl_xor(lsum, 32);
    float inv = 1.0f / lsum;

    // epilogue: O^T -> lk[qrel][d] -> coalesced stores
    __syncthreads();
    {
        int qrel = wv*16 + mn;
        #pragma unroll
        for (int rr = 0; rr < 4; ++rr) {
            lk[qrel*32 + quad*4 + rr]      = (__bf16)(oaccA[rr]*inv);
            lk[qrel*32 + 16 + quad*4 + rr] = (__bf16)(oaccB[rr]*inv);
        }
    }
    __syncthreads();
    {
        int r = tid >> 2, ch = tid & 3;
        int q = q0 + r;
        if (q < N_)
            *(bf16x8*)&o[((size_t)(b*N_ + q))*C_ + h*HD_ + ch*8] =
                *(const bf16x8*)&lk[r*32 + ch*8];
    }
}

// ---------------------------------------------------------------------------
// feat3: LDS 32x32 tile transpose (fp32). grid (54, 8, 4).
// ---------------------------------------------------------------------------
__global__ __launch_bounds__(256) void feat3(
    const float* __restrict__ y, float* __restrict__ outf)
{
    __shared__ float tl[32][33];
    int p0 = blockIdx.x*32, c0 = blockIdx.y*32, b = blockIdx.z;
    int cc = threadIdx.x & 31, rr = threadIdx.x >> 5;
    for (int i = rr; i < 32; i += 8)
        tl[i][cc] = y[((size_t)(b*N_) + 1 + p0 + i)*C_ + c0 + cc];
    __syncthreads();
    for (int i = rr; i < 32; i += 8)
        outf[((size_t)(b*C_) + c0 + i)*P_ + p0 + cc] = tl[cc][i];
}

// ---------------------------------------------------------------------------
extern "C" void kernel_launch(void* const* d_in, const int* in_sizes, int n_in,
                              void* d_out, int out_size, void* d_ws, size_t ws_size,
                              hipStream_t stream)
{
    const float* x        = (const float*)d_in[0];
    const float* W_pe     = (const float*)d_in[1];
    const float* b_pe     = (const float*)d_in[2];
    const float* cls_tok  = (const float*)d_in[3];
    const float* ln1_g    = (const float*)d_in[4];
    const float* ln1_b    = (const float*)d_in[5];
    const float* Wqkv     = (const float*)d_in[6];
    const float* Wproj    = (const float*)d_in[7];
    const float* bproj    = (const float*)d_in[8];
    const float* ln2_g    = (const float*)d_in[9];
    const float* ln2_b    = (const float*)d_in[10];
    const float* W1       = (const float*)d_in[11];
    const float* b1       = (const float*)d_in[12];
    const float* W2       = (const float*)d_in[13];
    const float* b2       = (const float*)d_in[14];
    const float* normf_g  = (const float*)d_in[15];
    const float* normf_b  = (const float*)d_in[16];

    const size_t MC = (size_t)M_*C_;    // 1,770,496
    float*  ws  = (float*)d_ws;
    float*  t   = ws;                               // MC fp32
    float*  yf  = ws + MC;                          // MC fp32 (final ln out)
    __bf16* ybf = (__bf16*)(ws + 2*MC);             // MC bf16
    __bf16* hbf = (__bf16*)(ws + 2*MC + MC/2);      // MC bf16
    __bf16* obf = (__bf16*)(ws + 2*MC + MC);        // MC bf16
    __bf16* wT  = (__bf16*)(ws + 2*MC + 3*(MC/2));  // 786432 bf16
    __bf16* qB  = wT + 2*768*256 + 6*256*256;       // [32][NPAD][32]
    __bf16* kB  = qB + (size_t)B_*NH_*NPAD*32;
    __bf16* vB  = kB + (size_t)B_*NH_*NPAD*32;      // [32][32][NPAD]

    __bf16* projT = wT + 2*768*256;
    __bf16* w1T   = projT + 2*256*256;
    __bf16* w2T   = w1T   + 2*256*256;

    float* out_cls  = (float*)d_out;
    float* out_feat = out_cls + B_*C_;

    wprep2<<<dim3(24, 8, 8), 256, 0, stream>>>(Wqkv, Wproj, W1, W2, wT);
    embed2<<<(B_*N_*C_)/256, 256, 0, stream>>>(x, W_pe, b_pe, cls_tok, t);

    const int GRID_M = (M_ + 63) / 64;   // 109
    for (int i = 0; i < 2; ++i) {
        ln4<<<M_/4, 256, 0, stream>>>(t, ybf, ln1_g + i*C_, ln1_b + i*C_);
        gemm_qkv3<<<dim3(GRID_M, 12), 256, 0, stream>>>(
            ybf, wT + (size_t)i*768*256, qB, kB, vB);
        attn9<<<dim3(32, 28), 256, 0, stream>>>(qB, kB, vB, obf);
        gemm3<256,true,false,true,false><<<dim3(GRID_M, 4), 256, 0, stream>>>(
            obf, projT + (size_t)i*65536, bproj + i*C_, t, nullptr);
        ln4<<<M_/4, 256, 0, stream>>>(t, ybf, ln2_g + i*C_, ln2_b + i*C_);
        gemm3<256,false,true,true,true><<<dim3(GRID_M, 4), 256, 0, stream>>>(
            ybf, w1T + (size_t)i*65536, b1 + i*C_, nullptr, hbf);
        gemm3<256,true,false,true,false><<<dim3(GRID_M, 4), 256, 0, stream>>>(
            hbf, w2T + (size_t)i*65536, b2 + i*C_, t, nullptr);
    }

    ln4f<<<M_/4, 256, 0, stream>>>(t, yf, normf_g, normf_b, out_cls);
    feat3<<<dim3(54, 8, 4), 256, 0, stream>>>(yf, out_feat);
}

// Round 14
// 303.428 us; speedup vs baseline: 1.0888x; 1.0888x over previous
//
#include <hip/hip_runtime.h>
#include <hip/hip_bf16.h>
#include <math.h>

#define B_   4
#define CIN  64
#define P_   1728
#define N_   1729
#define C_   256
#define NH_  8
#define HD_  32
#define M_   (B_*N_)   // 6916 rows
#define NPAD 1792      // 28 * 64

typedef __bf16 bf16x8 __attribute__((ext_vector_type(8)));
typedef __bf16 bf16x4 __attribute__((ext_vector_type(4)));
typedef float  f32x4  __attribute__((ext_vector_type(4)));

// ---------------------------------------------------------------------------
// Patch embed. One thread per (b, n, c). Writes t fp32.
// ---------------------------------------------------------------------------
__global__ __launch_bounds__(256) void embed2(
    const float* __restrict__ x, const float* __restrict__ Wpe,
    const float* __restrict__ bpe, const float* __restrict__ cls,
    float* __restrict__ t)
{
    int idx = blockIdx.x*256 + threadIdx.x;        // [0, B*N*C)
    int c   = idx & 255;
    int n   = (idx >> 8) % N_;
    int b   = idx / (N_*256);
    if (n == 0) { t[idx] = cls[c]; return; }
    int p = n - 1;
    float acc = bpe[c];
    for (int ci = 0; ci < CIN; ++ci)
        acc += x[(size_t)(b*CIN + ci)*P_ + p] * Wpe[ci*C_ + c];
    t[idx] = acc;
}

// ---------------------------------------------------------------------------
// ln4: LayerNorm, 4 rows/block (one wave each), float4 in, bf16x4 out.
// ---------------------------------------------------------------------------
__global__ __launch_bounds__(256) void ln4(
    const float* __restrict__ in, __bf16* __restrict__ out,
    const float* __restrict__ g, const float* __restrict__ bb)
{
    int wv = threadIdx.x >> 6, lane = threadIdx.x & 63;
    size_t row = (size_t)blockIdx.x*4 + wv;
    float4 v = *(const float4*)&in[row*C_ + lane*4];
    float s1 = (v.x+v.y)+(v.z+v.w);
    float s2 = (v.x*v.x+v.y*v.y)+(v.z*v.z+v.w*v.w);
    #pragma unroll
    for (int off = 32; off >= 1; off >>= 1) {
        s1 += __shfl_xor(s1, off);
        s2 += __shfl_xor(s2, off);
    }
    float mean = s1*(1.0f/C_);
    float var  = fmaxf(s2*(1.0f/C_) - mean*mean, 0.0f);
    float rstd = rsqrtf(var + 1e-5f);
    float4 gg = *(const float4*)&g[lane*4];
    float4 bv = *(const float4*)&bb[lane*4];
    bf16x4 r;
    r[0] = (__bf16)((v.x-mean)*rstd*gg.x + bv.x);
    r[1] = (__bf16)((v.y-mean)*rstd*gg.y + bv.y);
    r[2] = (__bf16)((v.z-mean)*rstd*gg.z + bv.z);
    r[3] = (__bf16)((v.w-mean)*rstd*gg.w + bv.w);
    *(bf16x4*)&out[row*C_ + lane*4] = r;
}

// ln4f: final norm — fp32 out + cls extraction.
__global__ __launch_bounds__(256) void ln4f(
    const float* __restrict__ in, float* __restrict__ out,
    const float* __restrict__ g, const float* __restrict__ bb,
    float* __restrict__ cls_out)
{
    int wv = threadIdx.x >> 6, lane = threadIdx.x & 63;
    size_t row = (size_t)blockIdx.x*4 + wv;
    float4 v = *(const float4*)&in[row*C_ + lane*4];
    float s1 = (v.x+v.y)+(v.z+v.w);
    float s2 = (v.x*v.x+v.y*v.y)+(v.z*v.z+v.w*v.w);
    #pragma unroll
    for (int off = 32; off >= 1; off >>= 1) {
        s1 += __shfl_xor(s1, off);
        s2 += __shfl_xor(s2, off);
    }
    float mean = s1*(1.0f/C_);
    float var  = fmaxf(s2*(1.0f/C_) - mean*mean, 0.0f);
    float rstd = rsqrtf(var + 1e-5f);
    float4 gg = *(const float4*)&g[lane*4];
    float4 bv = *(const float4*)&bb[lane*4];
    float4 r;
    r.x = (v.x-mean)*rstd*gg.x + bv.x;
    r.y = (v.y-mean)*rstd*gg.y + bv.y;
    r.z = (v.z-mean)*rstd*gg.z + bv.z;
    r.w = (v.w-mean)*rstd*gg.w + bv.w;
    *(float4*)&out[row*C_ + lane*4] = r;
    if ((row % N_) == 0)
        *(float4*)&cls_out[(row / N_)*C_ + lane*4] = r;
}

// ---------------------------------------------------------------------------
// wprep2: all 8 weight matrices -> bf16 W^T[n][k] in one launch.
// ---------------------------------------------------------------------------
__global__ __launch_bounds__(256) void wprep2(
    const float* __restrict__ Wqkv, const float* __restrict__ Wproj,
    const float* __restrict__ W1,   const float* __restrict__ W2,
    __bf16* __restrict__ wT)
{
    int z = blockIdx.z, which = z >> 1, layer = z & 1;
    const float* src; __bf16* dst; int NC;
    if (which == 0) {
        src = Wqkv + (size_t)layer*C_*768;
        dst = wT   + (size_t)layer*768*256;
        NC  = 768;
    } else {
        NC = 256;
        const float* b3 = (which == 1) ? Wproj : (which == 2) ? W1 : W2;
        src = b3 + (size_t)layer*65536;
        dst = wT + 2*768*256 + (size_t)((which-1)*2 + layer)*65536;
    }
    int n0 = blockIdx.x*32; if (n0 >= NC) return;
    int k0 = blockIdx.y*32;
    __shared__ float tile[32][33];
    int c = threadIdx.x & 31, r = threadIdx.x >> 5;
    for (int rr = r; rr < 32; rr += 8)
        tile[rr][c] = src[(size_t)(k0+rr)*NC + n0 + c];
    __syncthreads();
    for (int rr = r; rr < 32; rr += 8)
        dst[(size_t)(n0+rr)*256 + k0 + c] = (__bf16)tile[c][rr];
}

// ---------------------------------------------------------------------------
// gemm3: out[M,NC] (+)= A[M,256](bf16) @ WtT (+bias fp32)(gelu). 64x64 tile,
// BK=64 (4 k-iters, 8 barriers/block), XOR-swizzled dense LDS (stride 64,
// chunk c at c^(row&7)): staging writes + frag b128 reads both hit each bank
// exactly 8x (conflict-free) and stay 16B-aligned.
// ---------------------------------------------------------------------------
template<int NC, bool ADD, bool GELU, bool BIAS, bool OUTBF>
__global__ __launch_bounds__(256) void gemm3(
    const __bf16* __restrict__ A, const __bf16* __restrict__ Wt,
    const float* __restrict__ bias, float* __restrict__ outF,
    __bf16* __restrict__ outB)
{
    __shared__ __align__(16) __bf16 As[64*64];
    __shared__ __align__(16) __bf16 Bs[64*64];
    int r0 = blockIdx.x*64, c0 = blockIdx.y*64;
    int tid = threadIdx.x;
    int wv = tid >> 6, lane = tid & 63, quad = lane >> 4, mn = lane & 15;
    int sr = tid >> 2, sc = tid & 3;
    int ga = r0 + sr; if (ga >= M_) ga = M_ - 1;

    f32x4 acc[4];
    #pragma unroll
    for (int ct = 0; ct < 4; ++ct)
        #pragma unroll
        for (int rr = 0; rr < 4; ++rr) acc[ct][rr] = 0.f;

    for (int kc = 0; kc < 4; ++kc) {
        __syncthreads();
        *(bf16x8*)&As[sr*64 + ((sc ^ (sr & 7))*8)] =
            *(const bf16x8*)&A[(size_t)ga*256 + kc*64 + sc*8];
        *(bf16x8*)&As[sr*64 + (((sc+4) ^ (sr & 7))*8)] =
            *(const bf16x8*)&A[(size_t)ga*256 + kc*64 + sc*8 + 32];
        *(bf16x8*)&Bs[sr*64 + ((sc ^ (sr & 7))*8)] =
            *(const bf16x8*)&Wt[(size_t)(c0+sr)*256 + kc*64 + sc*8];
        *(bf16x8*)&Bs[sr*64 + (((sc+4) ^ (sr & 7))*8)] =
            *(const bf16x8*)&Wt[(size_t)(c0+sr)*256 + kc*64 + sc*8 + 32];
        __syncthreads();

        #pragma unroll
        for (int h = 0; h < 2; ++h) {
            bf16x8 a = *(const bf16x8*)&As[(wv*16 + mn)*64 + (((h*4+quad) ^ (mn & 7))*8)];
            #pragma unroll
            for (int ct = 0; ct < 4; ++ct) {
                bf16x8 b = *(const bf16x8*)&Bs[(ct*16 + mn)*64 + (((h*4+quad) ^ (mn & 7))*8)];
                acc[ct] = __builtin_amdgcn_mfma_f32_16x16x32_bf16(a, b, acc[ct], 0, 0, 0);
            }
        }
    }

    #pragma unroll
    for (int ct = 0; ct < 4; ++ct) {
        int col = c0 + ct*16 + mn;
        #pragma unroll
        for (int rr = 0; rr < 4; ++rr) {
            int row = r0 + wv*16 + quad*4 + rr;
            if (row >= M_) continue;
            float val = acc[ct][rr];
            if (BIAS) val += bias[col];
            if (GELU) val = 0.5f*val*(1.f + erff(val*0.70710678118654752f));
            size_t oi = (size_t)row*NC + col;
            if (OUTBF) outB[oi] = (__bf16)val;
            else if (ADD) outF[oi] += val;
            else outF[oi] = val;
        }
    }
}

// ---------------------------------------------------------------------------
// gemm_qkv3: BK=64 core; epilogue packs qB (scaled), kB, vB (transposed).
// ---------------------------------------------------------------------------
__global__ __launch_bounds__(256) void gemm_qkv3(
    const __bf16* __restrict__ A, const __bf16* __restrict__ Wt,
    __bf16* __restrict__ qB, __bf16* __restrict__ kB, __bf16* __restrict__ vB)
{
    __shared__ __align__(16) __bf16 As[64*64];
    __shared__ __align__(16) __bf16 Bs[64*64];
    int r0 = blockIdx.x*64, c0 = blockIdx.y*64;
    int tid = threadIdx.x;
    int wv = tid >> 6, lane = tid & 63, quad = lane >> 4, mn = lane & 15;
    int sr = tid >> 2, sc = tid & 3;
    int ga = r0 + sr; if (ga >= M_) ga = M_ - 1;

    f32x4 acc[4];
    #pragma unroll
    for (int ct = 0; ct < 4; ++ct)
        #pragma unroll
        for (int rr = 0; rr < 4; ++rr) acc[ct][rr] = 0.f;

    for (int kc = 0; kc < 4; ++kc) {
        __syncthreads();
        *(bf16x8*)&As[sr*64 + ((sc ^ (sr & 7))*8)] =
            *(const bf16x8*)&A[(size_t)ga*256 + kc*64 + sc*8];
        *(bf16x8*)&As[sr*64 + (((sc+4) ^ (sr & 7))*8)] =
            *(const bf16x8*)&A[(size_t)ga*256 + kc*64 + sc*8 + 32];
        *(bf16x8*)&Bs[sr*64 + ((sc ^ (sr & 7))*8)] =
            *(const bf16x8*)&Wt[(size_t)(c0+sr)*256 + kc*64 + sc*8];
        *(bf16x8*)&Bs[sr*64 + (((sc+4) ^ (sr & 7))*8)] =
            *(const bf16x8*)&Wt[(size_t)(c0+sr)*256 + kc*64 + sc*8 + 32];
        __syncthreads();

        #pragma unroll
        for (int h = 0; h < 2; ++h) {
            bf16x8 a = *(const bf16x8*)&As[(wv*16 + mn)*64 + (((h*4+quad) ^ (mn & 7))*8)];
            #pragma unroll
            for (int ct = 0; ct < 4; ++ct) {
                bf16x8 b = *(const bf16x8*)&Bs[(ct*16 + mn)*64 + (((h*4+quad) ^ (mn & 7))*8)];
                acc[ct] = __builtin_amdgcn_mfma_f32_16x16x32_bf16(a, b, acc[ct], 0, 0, 0);
            }
        }
    }

    const float scale = 0.17677669529663687f;   // 1/sqrt(32)
    #pragma unroll
    for (int ct = 0; ct < 4; ++ct) {
        int col = c0 + ct*16 + mn;
        #pragma unroll
        for (int rr = 0; rr < 4; ++rr) {
            int row = r0 + wv*16 + quad*4 + rr;
            if (row >= M_) continue;
            int b = row / N_, n = row - b*N_;
            float val = acc[ct][rr];
            if (col < 256) {
                int h = col >> 5, dd = col & 31;
                qB[((size_t)(b*NH_+h)*NPAD + n)*32 + dd] = (__bf16)(val*scale);
            } else if (col < 512) {
                int h = (col-256) >> 5, dd = col & 31;
                kB[((size_t)(b*NH_+h)*NPAD + n)*32 + dd] = (__bf16)val;
            } else {
                int h = (col-512) >> 5, dd = col & 31;
                vB[((size_t)(b*NH_+h)*32 + dd)*NPAD + n] = (__bf16)val;
            }
        }
    }
}

// ---------------------------------------------------------------------------
// attn10: attn8 (R12, proven) with TK=128 staging — one barrier pair per
// 128 keys, processed as two wave-local 64-key passes (lp is per-wave).
// XOR-swizzled dense lk/lvt; l via register ones-B-frag MFMA.
// ---------------------------------------------------------------------------
__global__ __launch_bounds__(256) void attn10(
    const __bf16* __restrict__ qB, const __bf16* __restrict__ kB,
    const __bf16* __restrict__ vB, __bf16* __restrict__ o)
{
    int bh = blockIdx.x, b = bh >> 3, h = bh & 7;
    int q0 = blockIdx.y * 64;
    int tid = threadIdx.x;
    int wv = tid >> 6, lane = tid & 63, quad = lane >> 4, mn = lane & 15;

    __shared__ __align__(16) __bf16 lk[128*32];    // [key][d] swizzled
    __shared__ __align__(16) __bf16 lvt[32*128];   // [d][key] swizzled
    __shared__ __align__(16) __bf16 lp[4][16*72];  // per-wave P, stride 72

    bf16x8 qfrag = *(const bf16x8*)(
        qB + ((size_t)bh*NPAD + q0 + wv*16 + mn)*32 + quad*8);

    bf16x8 vones;
    #pragma unroll
    for (int j = 0; j < 8; ++j) vones[j] = (mn == 0) ? (__bf16)1.0f : (__bf16)0.0f;

    f32x4 oacc0, oacc1, oacc2;
    #pragma unroll
    for (int rr = 0; rr < 4; ++rr) { oacc0[rr]=0.f; oacc1[rr]=0.f; oacc2[rr]=0.f; }

    const __bf16* kbase = kB + (size_t)bh*NPAD*32;
    const __bf16* vbase = vB + (size_t)bh*32*NPAD;
    int sr = tid >> 2, sc = tid & 3;     // K staging rows/chunks
    int vr = tid >> 3, vc = tid & 7;     // V^T staging rows/chunks

    for (int t = 0; t < 14; ++t) {
        int k0 = t*128;
        __syncthreads();
        #pragma unroll
        for (int hh = 0; hh < 2; ++hh) {
            int r = hh*64 + sr;
            *(bf16x8*)&lk[r*32 + ((sc ^ (r & 3))*8)] =
                *(const bf16x8*)(kbase + (size_t)(k0 + r)*32 + sc*8);
            int cp = hh*8 + vc;
            *(bf16x8*)&lvt[vr*128 + ((cp ^ (vr & 7))*8)] =
                *(const bf16x8*)(vbase + (size_t)vr*NPAD + k0 + cp*8);
        }
        __syncthreads();

        #pragma unroll
        for (int h2 = 0; h2 < 2; ++h2) {
            // S = Q K^T over this 64-key half
            f32x4 s[4];
            #pragma unroll
            for (int ct = 0; ct < 4; ++ct) {
                int kr = h2*64 + ct*16 + mn;                 // kr&3 == mn&3
                bf16x8 kf = *(const bf16x8*)&lk[kr*32 + ((quad ^ (mn & 3))*8)];
                f32x4 z;
                #pragma unroll
                for (int rr = 0; rr < 4; ++rr) z[rr] = 0.f;
                s[ct] = __builtin_amdgcn_mfma_f32_16x16x32_bf16(qfrag, kf, z, 0, 0, 0);
            }

            // P = exp(S), masked; per-wave LDS round-trip
            #pragma unroll
            for (int ct = 0; ct < 4; ++ct) {
                bool valid = (k0 + h2*64 + ct*16 + mn) < N_;
                #pragma unroll
                for (int rr = 0; rr < 4; ++rr) {
                    float p = valid ? __expf(s[ct][rr]) : 0.f;
                    lp[wv][(quad*4+rr)*72 + ct*16 + mn] = (__bf16)p;
                }
            }

            // O += P V ; l += P @ ones
            #pragma unroll
            for (int kh = 0; kh < 2; ++kh) {
                bf16x8 pf = *(const bf16x8*)&lp[wv][mn*72 + kh*32 + quad*8];
                int chunk = h2*8 + kh*4 + quad;
                int vsw = (chunk ^ (mn & 7)) * 8;
                bf16x8 v0 = *(const bf16x8*)&lvt[ mn      *128 + vsw];
                bf16x8 v1 = *(const bf16x8*)&lvt[(mn+16)*128 + vsw];
                oacc0 = __builtin_amdgcn_mfma_f32_16x16x32_bf16(pf, v0, oacc0, 0, 0, 0);
                oacc1 = __builtin_amdgcn_mfma_f32_16x16x32_bf16(pf, v1, oacc1, 0, 0, 0);
                oacc2 = __builtin_amdgcn_mfma_f32_16x16x32_bf16(pf, vones, oacc2, 0, 0, 0);
            }
        }
    }

    #pragma unroll
    for (int rr = 0; rr < 4; ++rr) {
        float l = __shfl(oacc2[rr], lane & 48);   // col 32 -> mn==0 lane of quad
        int q = q0 + wv*16 + quad*4 + rr;
        if (q >= N_) continue;
        float inv = 1.0f / l;
        size_t base = ((size_t)(b*N_ + q))*C_ + h*HD_;
        o[base + mn]      = (__bf16)(oacc0[rr]*inv);
        o[base + 16 + mn] = (__bf16)(oacc1[rr]*inv);
    }
}

// ---------------------------------------------------------------------------
// feat3: LDS 32x32 tile transpose (fp32). grid (54, 8, 4).
// ---------------------------------------------------------------------------
__global__ __launch_bounds__(256) void feat3(
    const float* __restrict__ y, float* __restrict__ outf)
{
    __shared__ float tl[32][33];
    int p0 = blockIdx.x*32, c0 = blockIdx.y*32, b = blockIdx.z;
    int cc = threadIdx.x & 31, rr = threadIdx.x >> 5;
    for (int i = rr; i < 32; i += 8)
        tl[i][cc] = y[((size_t)(b*N_) + 1 + p0 + i)*C_ + c0 + cc];
    __syncthreads();
    for (int i = rr; i < 32; i += 8)
        outf[((size_t)(b*C_) + c0 + i)*P_ + p0 + cc] = tl[cc][i];
}

// ---------------------------------------------------------------------------
extern "C" void kernel_launch(void* const* d_in, const int* in_sizes, int n_in,
                              void* d_out, int out_size, void* d_ws, size_t ws_size,
                              hipStream_t stream)
{
    const float* x        = (const float*)d_in[0];
    const float* W_pe     = (const float*)d_in[1];
    const float* b_pe     = (const float*)d_in[2];
    const float* cls_tok  = (const float*)d_in[3];
    const float* ln1_g    = (const float*)d_in[4];
    const float* ln1_b    = (const float*)d_in[5];
    const float* Wqkv     = (const float*)d_in[6];
    const float* Wproj    = (const float*)d_in[7];
    const float* bproj    = (const float*)d_in[8];
    const float* ln2_g    = (const float*)d_in[9];
    const float* ln2_b    = (const float*)d_in[10];
    const float* W1       = (const float*)d_in[11];
    const float* b1       = (const float*)d_in[12];
    const float* W2       = (const float*)d_in[13];
    const float* b2       = (const float*)d_in[14];
    const float* normf_g  = (const float*)d_in[15];
    const float* normf_b  = (const float*)d_in[16];

    const size_t MC = (size_t)M_*C_;    // 1,770,496
    float*  ws  = (float*)d_ws;
    float*  t   = ws;                               // MC fp32
    float*  yf  = ws + MC;                          // MC fp32 (final ln out)
    __bf16* ybf = (__bf16*)(ws + 2*MC);             // MC bf16
    __bf16* hbf = (__bf16*)(ws + 2*MC + MC/2);      // MC bf16
    __bf16* obf = (__bf16*)(ws + 2*MC + MC);        // MC bf16
    __bf16* wT  = (__bf16*)(ws + 2*MC + 3*(MC/2));  // 786432 bf16
    __bf16* qB  = wT + 2*768*256 + 6*256*256;       // [32][NPAD][32]
    __bf16* kB  = qB + (size_t)B_*NH_*NPAD*32;
    __bf16* vB  = kB + (size_t)B_*NH_*NPAD*32;      // [32][32][NPAD]

    __bf16* projT = wT + 2*768*256;
    __bf16* w1T   = projT + 2*256*256;
    __bf16* w2T   = w1T   + 2*256*256;

    float* out_cls  = (float*)d_out;
    float* out_feat = out_cls + B_*C_;

    wprep2<<<dim3(24, 8, 8), 256, 0, stream>>>(Wqkv, Wproj, W1, W2, wT);
    embed2<<<(B_*N_*C_)/256, 256, 0, stream>>>(x, W_pe, b_pe, cls_tok, t);

    const int GRID_M = (M_ + 63) / 64;   // 109
    for (int i = 0; i < 2; ++i) {
        ln4<<<M_/4, 256, 0, stream>>>(t, ybf, ln1_g + i*C_, ln1_b + i*C_);
        gemm_qkv3<<<dim3(GRID_M, 12), 256, 0, stream>>>(
            ybf, wT + (size_t)i*768*256, qB, kB, vB);
        attn10<<<dim3(32, 28), 256, 0, stream>>>(qB, kB, vB, obf);
        gemm3<256,true,false,true,false><<<dim3(GRID_M, 4), 256, 0, stream>>>(
            obf, projT + (size_t)i*65536, bproj + i*C_, t, nullptr);
        ln4<<<M_/4, 256, 0, stream>>>(t, ybf, ln2_g + i*C_, ln2_b + i*C_);
        gemm3<256,false,true,true,true><<<dim3(GRID_M, 4), 256, 0, stream>>>(
            ybf, w1T + (size_t)i*65536, b1 + i*C_, nullptr, hbf);
        gemm3<256,true,false,true,false><<<dim3(GRID_M, 4), 256, 0, stream>>>(
            hbf, w2T + (size_t)i*65536, b2 + i*C_, t, nullptr);
    }

    ln4f<<<M_/4, 256, 0, stream>>>(t, yf, normf_g, normf_b, out_cls);
    feat3<<<dim3(54, 8, 4), 256, 0, stream>>>(yf, out_feat);
}

// Round 15
// 293.408 us; speedup vs baseline: 1.1260x; 1.0341x over previous
//
#include <hip/hip_runtime.h>
#include <hip/hip_bf16.h>
#include <math.h>

#define B_   4
#define CIN  64
#define P_   1728
#define N_   1729
#define C_   256
#define NH_  8
#define HD_  32
#define M_   (B_*N_)   // 6916 rows
#define NPAD 1792      // 28 * 64

typedef __bf16 bf16x8 __attribute__((ext_vector_type(8)));
typedef __bf16 bf16x4 __attribute__((ext_vector_type(4)));
typedef float  f32x4  __attribute__((ext_vector_type(4)));

// ---------------------------------------------------------------------------
// Patch embed. One thread per (b, n, c). Writes t fp32.
// ---------------------------------------------------------------------------
__global__ __launch_bounds__(256) void embed2(
    const float* __restrict__ x, const float* __restrict__ Wpe,
    const float* __restrict__ bpe, const float* __restrict__ cls,
    float* __restrict__ t)
{
    int idx = blockIdx.x*256 + threadIdx.x;        // [0, B*N*C)
    int c   = idx & 255;
    int n   = (idx >> 8) % N_;
    int b   = idx / (N_*256);
    if (n == 0) { t[idx] = cls[c]; return; }
    int p = n - 1;
    float acc = bpe[c];
    for (int ci = 0; ci < CIN; ++ci)
        acc += x[(size_t)(b*CIN + ci)*P_ + p] * Wpe[ci*C_ + c];
    t[idx] = acc;
}

// ---------------------------------------------------------------------------
// ln4: LayerNorm, 4 rows/block (one wave each), float4 in, bf16x4 out.
// ---------------------------------------------------------------------------
__global__ __launch_bounds__(256) void ln4(
    const float* __restrict__ in, __bf16* __restrict__ out,
    const float* __restrict__ g, const float* __restrict__ bb)
{
    int wv = threadIdx.x >> 6, lane = threadIdx.x & 63;
    size_t row = (size_t)blockIdx.x*4 + wv;
    float4 v = *(const float4*)&in[row*C_ + lane*4];
    float s1 = (v.x+v.y)+(v.z+v.w);
    float s2 = (v.x*v.x+v.y*v.y)+(v.z*v.z+v.w*v.w);
    #pragma unroll
    for (int off = 32; off >= 1; off >>= 1) {
        s1 += __shfl_xor(s1, off);
        s2 += __shfl_xor(s2, off);
    }
    float mean = s1*(1.0f/C_);
    float var  = fmaxf(s2*(1.0f/C_) - mean*mean, 0.0f);
    float rstd = rsqrtf(var + 1e-5f);
    float4 gg = *(const float4*)&g[lane*4];
    float4 bv = *(const float4*)&bb[lane*4];
    bf16x4 r;
    r[0] = (__bf16)((v.x-mean)*rstd*gg.x + bv.x);
    r[1] = (__bf16)((v.y-mean)*rstd*gg.y + bv.y);
    r[2] = (__bf16)((v.z-mean)*rstd*gg.z + bv.z);
    r[3] = (__bf16)((v.w-mean)*rstd*gg.w + bv.w);
    *(bf16x4*)&out[row*C_ + lane*4] = r;
}

// ln4f: final norm — fp32 out + cls extraction.
__global__ __launch_bounds__(256) void ln4f(
    const float* __restrict__ in, float* __restrict__ out,
    const float* __restrict__ g, const float* __restrict__ bb,
    float* __restrict__ cls_out)
{
    int wv = threadIdx.x >> 6, lane = threadIdx.x & 63;
    size_t row = (size_t)blockIdx.x*4 + wv;
    float4 v = *(const float4*)&in[row*C_ + lane*4];
    float s1 = (v.x+v.y)+(v.z+v.w);
    float s2 = (v.x*v.x+v.y*v.y)+(v.z*v.z+v.w*v.w);
    #pragma unroll
    for (int off = 32; off >= 1; off >>= 1) {
        s1 += __shfl_xor(s1, off);
        s2 += __shfl_xor(s2, off);
    }
    float mean = s1*(1.0f/C_);
    float var  = fmaxf(s2*(1.0f/C_) - mean*mean, 0.0f);
    float rstd = rsqrtf(var + 1e-5f);
    float4 gg = *(const float4*)&g[lane*4];
    float4 bv = *(const float4*)&bb[lane*4];
    float4 r;
    r.x = (v.x-mean)*rstd*gg.x + bv.x;
    r.y = (v.y-mean)*rstd*gg.y + bv.y;
    r.z = (v.z-mean)*rstd*gg.z + bv.z;
    r.w = (v.w-mean)*rstd*gg.w + bv.w;
    *(float4*)&out[row*C_ + lane*4] = r;
    if ((row % N_) == 0)
        *(float4*)&cls_out[(row / N_)*C_ + lane*4] = r;
}

// ---------------------------------------------------------------------------
// wprep2: all 8 weight matrices -> bf16 W^T[n][k] in one launch.
// ---------------------------------------------------------------------------
__global__ __launch_bounds__(256) void wprep2(
    const float* __restrict__ Wqkv, const float* __restrict__ Wproj,
    const float* __restrict__ W1,   const float* __restrict__ W2,
    __bf16* __restrict__ wT)
{
    int z = blockIdx.z, which = z >> 1, layer = z & 1;
    const float* src; __bf16* dst; int NC;
    if (which == 0) {
        src = Wqkv + (size_t)layer*C_*768;
        dst = wT   + (size_t)layer*768*256;
        NC  = 768;
    } else {
        NC = 256;
        const float* b3 = (which == 1) ? Wproj : (which == 2) ? W1 : W2;
        src = b3 + (size_t)layer*65536;
        dst = wT + 2*768*256 + (size_t)((which-1)*2 + layer)*65536;
    }
    int n0 = blockIdx.x*32; if (n0 >= NC) return;
    int k0 = blockIdx.y*32;
    __shared__ float tile[32][33];
    int c = threadIdx.x & 31, r = threadIdx.x >> 5;
    for (int rr = r; rr < 32; rr += 8)
        tile[rr][c] = src[(size_t)(k0+rr)*NC + n0 + c];
    __syncthreads();
    for (int rr = r; rr < 32; rr += 8)
        dst[(size_t)(n0+rr)*256 + k0 + c] = (__bf16)tile[c][rr];
}

// ---------------------------------------------------------------------------
// padzero: zero kB/vB pad rows (n in [N_, NPAD)) so attention needs no
// masking: pad keys add exp(0)=1 to l (subtracted as constant 63) and 0 to O.
// ---------------------------------------------------------------------------
__global__ __launch_bounds__(256) void padzero(
    __bf16* __restrict__ kB, __bf16* __restrict__ vB)
{
    int idx = blockIdx.x*256 + threadIdx.x;     // over 32*63*32 = 64512
    if (idx >= 32*63*32) return;
    int d  = idx & 31;
    int n  = (idx >> 5) % 63 + N_;
    int bh = idx / (63*32);
    kB[((size_t)bh*NPAD + n)*32 + d] = (__bf16)0.f;
    vB[((size_t)bh*32 + d)*NPAD + n] = (__bf16)0.f;
}

// ---------------------------------------------------------------------------
// gemm3: out[M,NC] (+)= A[M,256](bf16) @ WtT (+bias fp32)(gelu). 64x64 tile,
// BK=64 (4 k-iters), XOR-swizzled dense LDS (chunk c at c^(row&7)).
// ---------------------------------------------------------------------------
template<int NC, bool ADD, bool GELU, bool BIAS, bool OUTBF>
__global__ __launch_bounds__(256) void gemm3(
    const __bf16* __restrict__ A, const __bf16* __restrict__ Wt,
    const float* __restrict__ bias, float* __restrict__ outF,
    __bf16* __restrict__ outB)
{
    __shared__ __align__(16) __bf16 As[64*64];
    __shared__ __align__(16) __bf16 Bs[64*64];
    int r0 = blockIdx.x*64, c0 = blockIdx.y*64;
    int tid = threadIdx.x;
    int wv = tid >> 6, lane = tid & 63, quad = lane >> 4, mn = lane & 15;
    int sr = tid >> 2, sc = tid & 3;
    int ga = r0 + sr; if (ga >= M_) ga = M_ - 1;

    f32x4 acc[4];
    #pragma unroll
    for (int ct = 0; ct < 4; ++ct)
        #pragma unroll
        for (int rr = 0; rr < 4; ++rr) acc[ct][rr] = 0.f;

    for (int kc = 0; kc < 4; ++kc) {
        __syncthreads();
        *(bf16x8*)&As[sr*64 + ((sc ^ (sr & 7))*8)] =
            *(const bf16x8*)&A[(size_t)ga*256 + kc*64 + sc*8];
        *(bf16x8*)&As[sr*64 + (((sc+4) ^ (sr & 7))*8)] =
            *(const bf16x8*)&A[(size_t)ga*256 + kc*64 + sc*8 + 32];
        *(bf16x8*)&Bs[sr*64 + ((sc ^ (sr & 7))*8)] =
            *(const bf16x8*)&Wt[(size_t)(c0+sr)*256 + kc*64 + sc*8];
        *(bf16x8*)&Bs[sr*64 + (((sc+4) ^ (sr & 7))*8)] =
            *(const bf16x8*)&Wt[(size_t)(c0+sr)*256 + kc*64 + sc*8 + 32];
        __syncthreads();

        #pragma unroll
        for (int h = 0; h < 2; ++h) {
            bf16x8 a = *(const bf16x8*)&As[(wv*16 + mn)*64 + (((h*4+quad) ^ (mn & 7))*8)];
            #pragma unroll
            for (int ct = 0; ct < 4; ++ct) {
                bf16x8 b = *(const bf16x8*)&Bs[(ct*16 + mn)*64 + (((h*4+quad) ^ (mn & 7))*8)];
                acc[ct] = __builtin_amdgcn_mfma_f32_16x16x32_bf16(a, b, acc[ct], 0, 0, 0);
            }
        }
    }

    #pragma unroll
    for (int ct = 0; ct < 4; ++ct) {
        int col = c0 + ct*16 + mn;
        #pragma unroll
        for (int rr = 0; rr < 4; ++rr) {
            int row = r0 + wv*16 + quad*4 + rr;
            if (row >= M_) continue;
            float val = acc[ct][rr];
            if (BIAS) val += bias[col];
            if (GELU) val = 0.5f*val*(1.f + erff(val*0.70710678118654752f));
            size_t oi = (size_t)row*NC + col;
            if (OUTBF) outB[oi] = (__bf16)val;
            else if (ADD) outF[oi] += val;
            else outF[oi] = val;
        }
    }
}

// ---------------------------------------------------------------------------
// gemm_qkv3: BK=64 core; epilogue packs qB (scaled), kB, vB (transposed).
// ---------------------------------------------------------------------------
__global__ __launch_bounds__(256) void gemm_qkv3(
    const __bf16* __restrict__ A, const __bf16* __restrict__ Wt,
    __bf16* __restrict__ qB, __bf16* __restrict__ kB, __bf16* __restrict__ vB)
{
    __shared__ __align__(16) __bf16 As[64*64];
    __shared__ __align__(16) __bf16 Bs[64*64];
    int r0 = blockIdx.x*64, c0 = blockIdx.y*64;
    int tid = threadIdx.x;
    int wv = tid >> 6, lane = tid & 63, quad = lane >> 4, mn = lane & 15;
    int sr = tid >> 2, sc = tid & 3;
    int ga = r0 + sr; if (ga >= M_) ga = M_ - 1;

    f32x4 acc[4];
    #pragma unroll
    for (int ct = 0; ct < 4; ++ct)
        #pragma unroll
        for (int rr = 0; rr < 4; ++rr) acc[ct][rr] = 0.f;

    for (int kc = 0; kc < 4; ++kc) {
        __syncthreads();
        *(bf16x8*)&As[sr*64 + ((sc ^ (sr & 7))*8)] =
            *(const bf16x8*)&A[(size_t)ga*256 + kc*64 + sc*8];
        *(bf16x8*)&As[sr*64 + (((sc+4) ^ (sr & 7))*8)] =
            *(const bf16x8*)&A[(size_t)ga*256 + kc*64 + sc*8 + 32];
        *(bf16x8*)&Bs[sr*64 + ((sc ^ (sr & 7))*8)] =
            *(const bf16x8*)&Wt[(size_t)(c0+sr)*256 + kc*64 + sc*8];
        *(bf16x8*)&Bs[sr*64 + (((sc+4) ^ (sr & 7))*8)] =
            *(const bf16x8*)&Wt[(size_t)(c0+sr)*256 + kc*64 + sc*8 + 32];
        __syncthreads();

        #pragma unroll
        for (int h = 0; h < 2; ++h) {
            bf16x8 a = *(const bf16x8*)&As[(wv*16 + mn)*64 + (((h*4+quad) ^ (mn & 7))*8)];
            #pragma unroll
            for (int ct = 0; ct < 4; ++ct) {
                bf16x8 b = *(const bf16x8*)&Bs[(ct*16 + mn)*64 + (((h*4+quad) ^ (mn & 7))*8)];
                acc[ct] = __builtin_amdgcn_mfma_f32_16x16x32_bf16(a, b, acc[ct], 0, 0, 0);
            }
        }
    }

    const float scale = 0.17677669529663687f;   // 1/sqrt(32)
    #pragma unroll
    for (int ct = 0; ct < 4; ++ct) {
        int col = c0 + ct*16 + mn;
        #pragma unroll
        for (int rr = 0; rr < 4; ++rr) {
            int row = r0 + wv*16 + quad*4 + rr;
            if (row >= M_) continue;
            int b = row / N_, n = row - b*N_;
            float val = acc[ct][rr];
            if (col < 256) {
                int h = col >> 5, dd = col & 31;
                qB[((size_t)(b*NH_+h)*NPAD + n)*32 + dd] = (__bf16)(val*scale);
            } else if (col < 512) {
                int h = (col-256) >> 5, dd = col & 31;
                kB[((size_t)(b*NH_+h)*NPAD + n)*32 + dd] = (__bf16)val;
            } else {
                int h = (col-512) >> 5, dd = col & 31;
                vB[((size_t)(b*NH_+h)*32 + dd)*NPAD + n] = (__bf16)val;
            }
        }
    }
}

// ---------------------------------------------------------------------------
// attn11: attn10 with (1) S^T operand order (mfma(kf,qfrag)) so each lane's
// 4 P values are key-contiguous -> ONE packed b64 lp write per ct (was 4 b16);
// (2) no masking (kB/vB pad rows zeroed by padzero; l -= 63 exactly);
// (3) l via VALU sums on S^T + end shuffles (ones-MFMA dropped).
// lp layout [q][key] stride 72 and PV MFMA32 path identical to attn10.
// ---------------------------------------------------------------------------
__global__ __launch_bounds__(256) void attn11(
    const __bf16* __restrict__ qB, const __bf16* __restrict__ kB,
    const __bf16* __restrict__ vB, __bf16* __restrict__ o)
{
    int bh = blockIdx.x, b = bh >> 3, h = bh & 7;
    int q0 = blockIdx.y * 64;
    int tid = threadIdx.x;
    int wv = tid >> 6, lane = tid & 63, quad = lane >> 4, mn = lane & 15;

    __shared__ __align__(16) __bf16 lk[128*32];    // [key][d] swizzled
    __shared__ __align__(16) __bf16 lvt[32*128];   // [d][key] swizzled
    __shared__ __align__(16) __bf16 lp[4][16*72];  // per-wave P [q][key], stride 72

    bf16x8 qfrag = *(const bf16x8*)(
        qB + ((size_t)bh*NPAD + q0 + wv*16 + mn)*32 + quad*8);

    f32x4 oacc0, oacc1;
    #pragma unroll
    for (int rr = 0; rr < 4; ++rr) { oacc0[rr]=0.f; oacc1[rr]=0.f; }
    float lsum = 0.f;

    const __bf16* kbase = kB + (size_t)bh*NPAD*32;
    const __bf16* vbase = vB + (size_t)bh*32*NPAD;
    int sr = tid >> 2, sc = tid & 3;     // K staging rows/chunks
    int vr = tid >> 3, vc = tid & 7;     // V^T staging rows/chunks

    for (int t = 0; t < 14; ++t) {
        int k0 = t*128;
        __syncthreads();
        #pragma unroll
        for (int hh = 0; hh < 2; ++hh) {
            int r = hh*64 + sr;
            *(bf16x8*)&lk[r*32 + ((sc ^ (r & 3))*8)] =
                *(const bf16x8*)(kbase + (size_t)(k0 + r)*32 + sc*8);
            int cp = hh*8 + vc;
            *(bf16x8*)&lvt[vr*128 + ((cp ^ (vr & 7))*8)] =
                *(const bf16x8*)(vbase + (size_t)vr*NPAD + k0 + cp*8);
        }
        __syncthreads();

        #pragma unroll
        for (int h2 = 0; h2 < 2; ++h2) {
            // S^T: A = K rows, B = Q -> lane holds P[key=ct*16+quad*4+rr][q=mn]
            #pragma unroll
            for (int ct = 0; ct < 4; ++ct) {
                int kr = h2*64 + ct*16 + mn;                 // kr&3 == mn&3
                bf16x8 kf = *(const bf16x8*)&lk[kr*32 + ((quad ^ (mn & 3))*8)];
                f32x4 z;
                #pragma unroll
                for (int rr = 0; rr < 4; ++rr) z[rr] = 0.f;
                f32x4 st = __builtin_amdgcn_mfma_f32_16x16x32_bf16(kf, qfrag, z, 0, 0, 0);

                bf16x4 pf4;
                #pragma unroll
                for (int rr = 0; rr < 4; ++rr) {
                    float p = __expf(st[rr]);
                    pf4[rr] = (__bf16)p;
                    lsum += p;
                }
                // keys ct*16+quad*4..+3 at row q=mn -> contiguous b64
                *(bf16x4*)&lp[wv][mn*72 + ct*16 + quad*4] = pf4;
            }

            // O += P V  (PV unchanged: A=P[q][key], B=V^T)
            #pragma unroll
            for (int kh = 0; kh < 2; ++kh) {
                bf16x8 pf = *(const bf16x8*)&lp[wv][mn*72 + kh*32 + quad*8];
                int chunk = h2*8 + kh*4 + quad;
                int vsw = (chunk ^ (mn & 7)) * 8;
                bf16x8 v0 = *(const bf16x8*)&lvt[ mn      *128 + vsw];
                bf16x8 v1 = *(const bf16x8*)&lvt[(mn+16)*128 + vsw];
                oacc0 = __builtin_amdgcn_mfma_f32_16x16x32_bf16(pf, v0, oacc0, 0, 0, 0);
                oacc1 = __builtin_amdgcn_mfma_f32_16x16x32_bf16(pf, v1, oacc1, 0, 0, 0);
            }
        }
    }

    // l(q=mn): reduce over quads, subtract the 63 pad-key exp(0) contributions
    lsum += __shfl_xor(lsum, 16);
    lsum += __shfl_xor(lsum, 32);
    lsum -= 63.0f;

    #pragma unroll
    for (int rr = 0; rr < 4; ++rr) {
        float l = __shfl(lsum, quad*4 + rr);   // lane q'=quad*4+rr holds l(q')
        int q = q0 + wv*16 + quad*4 + rr;
        if (q >= N_) continue;
        float inv = 1.0f / l;
        size_t base = ((size_t)(b*N_ + q))*C_ + h*HD_;
        o[base + mn]      = (__bf16)(oacc0[rr]*inv);
        o[base + 16 + mn] = (__bf16)(oacc1[rr]*inv);
    }
}

// ---------------------------------------------------------------------------
// feat3: LDS 32x32 tile transpose (fp32). grid (54, 8, 4).
// ---------------------------------------------------------------------------
__global__ __launch_bounds__(256) void feat3(
    const float* __restrict__ y, float* __restrict__ outf)
{
    __shared__ float tl[32][33];
    int p0 = blockIdx.x*32, c0 = blockIdx.y*32, b = blockIdx.z;
    int cc = threadIdx.x & 31, rr = threadIdx.x >> 5;
    for (int i = rr; i < 32; i += 8)
        tl[i][cc] = y[((size_t)(b*N_) + 1 + p0 + i)*C_ + c0 + cc];
    __syncthreads();
    for (int i = rr; i < 32; i += 8)
        outf[((size_t)(b*C_) + c0 + i)*P_ + p0 + cc] = tl[cc][i];
}

// ---------------------------------------------------------------------------
extern "C" void kernel_launch(void* const* d_in, const int* in_sizes, int n_in,
                              void* d_out, int out_size, void* d_ws, size_t ws_size,
                              hipStream_t stream)
{
    const float* x        = (const float*)d_in[0];
    const float* W_pe     = (const float*)d_in[1];
    const float* b_pe     = (const float*)d_in[2];
    const float* cls_tok  = (const float*)d_in[3];
    const float* ln1_g    = (const float*)d_in[4];
    const float* ln1_b    = (const float*)d_in[5];
    const float* Wqkv     = (const float*)d_in[6];
    const float* Wproj    = (const float*)d_in[7];
    const float* bproj    = (const float*)d_in[8];
    const float* ln2_g    = (const float*)d_in[9];
    const float* ln2_b    = (const float*)d_in[10];
    const float* W1       = (const float*)d_in[11];
    const float* b1       = (const float*)d_in[12];
    const float* W2       = (const float*)d_in[13];
    const float* b2       = (const float*)d_in[14];
    const float* normf_g  = (const float*)d_in[15];
    const float* normf_b  = (const float*)d_in[16];

    const size_t MC = (size_t)M_*C_;    // 1,770,496
    float*  ws  = (float*)d_ws;
    float*  t   = ws;                               // MC fp32
    float*  yf  = ws + MC;                          // MC fp32 (final ln out)
    __bf16* ybf = (__bf16*)(ws + 2*MC);             // MC bf16
    __bf16* hbf = (__bf16*)(ws + 2*MC + MC/2);      // MC bf16
    __bf16* obf = (__bf16*)(ws + 2*MC + MC);        // MC bf16
    __bf16* wT  = (__bf16*)(ws + 2*MC + 3*(MC/2));  // 786432 bf16
    __bf16* qB  = wT + 2*768*256 + 6*256*256;       // [32][NPAD][32]
    __bf16* kB  = qB + (size_t)B_*NH_*NPAD*32;
    __bf16* vB  = kB + (size_t)B_*NH_*NPAD*32;      // [32][32][NPAD]

    __bf16* projT = wT + 2*768*256;
    __bf16* w1T   = projT + 2*256*256;
    __bf16* w2T   = w1T   + 2*256*256;

    float* out_cls  = (float*)d_out;
    float* out_feat = out_cls + B_*C_;

    wprep2<<<dim3(24, 8, 8), 256, 0, stream>>>(Wqkv, Wproj, W1, W2, wT);
    padzero<<<252, 256, 0, stream>>>(kB, vB);
    embed2<<<(B_*N_*C_)/256, 256, 0, stream>>>(x, W_pe, b_pe, cls_tok, t);

    const int GRID_M = (M_ + 63) / 64;   // 109
    for (int i = 0; i < 2; ++i) {
        ln4<<<M_/4, 256, 0, stream>>>(t, ybf, ln1_g + i*C_, ln1_b + i*C_);
        gemm_qkv3<<<dim3(GRID_M, 12), 256, 0, stream>>>(
            ybf, wT + (size_t)i*768*256, qB, kB, vB);
        attn11<<<dim3(32, 28), 256, 0, stream>>>(qB, kB, vB, obf);
        gemm3<256,true,false,true,false><<<dim3(GRID_M, 4), 256, 0, stream>>>(
            obf, projT + (size_t)i*65536, bproj + i*C_, t, nullptr);
        ln4<<<M_/4, 256, 0, stream>>>(t, ybf, ln2_g + i*C_, ln2_b + i*C_);
        gemm3<256,false,true,true,true><<<dim3(GRID_M, 4), 256, 0, stream>>>(
            ybf, w1T + (size_t)i*65536, b1 + i*C_, nullptr, hbf);
        gemm3<256,true,false,true,false><<<dim3(GRID_M, 4), 256, 0, stream>>>(
            hbf, w2T + (size_t)i*65536, b2 + i*C_, t, nullptr);
    }

    ln4f<<<M_/4, 256, 0, stream>>>(t, yf, normf_g, normf_b, out_cls);
    feat3<<<dim3(54, 8, 4), 256, 0, stream>>>(yf, out_feat);
}